// Round 15
// baseline (67.078 us; speedup 1.0000x reference)
//
#include <hip/hip_runtime.h>

// QANet block. B=16 D=128 LC=2048 LQ=256.
// R1: proj -> bf16 MFMA.                         711 -> 318 us
// R2: rowpass -> fused bf16 MFMA.                318 -> 159 us
// R3/R4: column path -> MFMA + bf16 (no max).    159 us
// R5: S -> MFMA, fp32 Sdot gone.                 159 -> 100 us
// R6: fusion: 11 -> 6 dispatches, F in LDS.      100 -> 84.5 us
// R7: S recomputed in consumers, 4 dispatches.   84.5 -> 79.5 us
// R8: reg-operand S + j-chunked pipeline.        REGRESSED 88 us
// R9/R10: LDS diets.                             ~82 us — LDS was NOT the cap
// R11: unified VGPR+AGPR was the cap (launch_bounds(256,2)). 67 us.
// R12: direct-global M/W frags.                  REGRESSED 74 us (latency exposed)
// R13: revert to R11 + T5 setprio on MFMA.       66.1 us. BEST.
// R14: k_sctcmm double-buffered chunk staging (CWb[2]/Csb[2], 80KB LDS — free at
//      1 blk/CU since grid==256): stage(c+1) issued at top of chunk c, hidden
//      under S-MFMA+e+P-MFMA; barriers 32 -> 25. rowproj/prep/red untouched.

#define B_ 16
#define D_ 128
#define LC_ 2048
#define LQ_ 256
#define NEGV -1e30f

typedef float f4 __attribute__((ext_vector_type(4)));
typedef float f32x4 __attribute__((ext_vector_type(4)));
typedef short bfrag __attribute__((ext_vector_type(8)));
typedef unsigned short us4 __attribute__((ext_vector_type(4)));

__device__ __forceinline__ unsigned short f2b(float x) {
    unsigned u = __float_as_uint(x);
    u += 0x7fff + ((u >> 16) & 1);
    return (unsigned short)(u >> 16);
}

__device__ __forceinline__ float b2f(short s) {
    return __uint_as_float(((unsigned)(unsigned short)s) << 16);
}

__device__ __forceinline__ void gld16(const void* g, void* l) {
    __builtin_amdgcn_global_load_lds(
        (const __attribute__((address_space(1))) unsigned*)g,
        (__attribute__((address_space(3))) unsigned*)l, 16, 0, 0);
}

// merged prep: blocks [0,512): C-side; [512,576): Q-side
__global__ __launch_bounds__(256) void k_prep(const float* __restrict__ C,
        const float* __restrict__ Q, const float* __restrict__ w,
        const int* __restrict__ cmask, const int* __restrict__ qmask,
        const float* __restrict__ W_res,
        unsigned short* __restrict__ Cbf, unsigned short* __restrict__ Cwt,
        unsigned short* __restrict__ Qt, unsigned short* __restrict__ Mb,
        unsigned short* __restrict__ Wb, float* __restrict__ rC,
        float* __restrict__ rQ) {
    __shared__ float T[128][64];
    __shared__ float red[4][64];
    int tid = threadIdx.x;
    if (blockIdx.x < 512) {
        int b = blockIdx.x >> 5, i0 = (blockIdx.x & 31) * 64;
        int ii = tid & 63, db = tid >> 6;
        if (tid < 128) {
            int wo = blockIdx.x * 128 + tid;
            Wb[wo] = f2b(W_res[wo]);
        }
#pragma unroll
        for (int k = 0; k < 32; ++k) {
            int dd = db + 4 * k;
            float raw = C[((size_t)b * D_ + dd) * LC_ + i0 + ii];
            T[dd][ii] = raw;
            Cbf[((size_t)b * D_ + dd) * LC_ + i0 + ii] = f2b(raw);
        }
        __syncthreads();
        {
            float p = 0.f;
#pragma unroll
            for (int k = 0; k < 32; ++k) p += w[db * 32 + k] * T[db * 32 + k][ii];
            red[db][ii] = p;
        }
        int dq = db * 32;
#pragma unroll
        for (int m = 0; m < 8; ++m) {
            us4 v;
#pragma unroll
            for (int e = 0; e < 4; ++e) {
                int d = dq + m * 4 + e;
                v[e] = f2b(w[2 * D_ + d] * T[d][ii]);
            }
            *(us4*)&Cwt[((size_t)(b * LC_ + i0 + ii)) * D_ + dq + m * 4] = v;
        }
        __syncthreads();
        if (tid < 64) {
            int gi = b * LC_ + i0 + tid;
            rC[gi] = red[0][tid] + red[1][tid] + red[2][tid] + red[3][tid]
                   + (cmask[gi] ? 0.f : NEGV);
        }
    } else {
        int bq = blockIdx.x - 512;
        int b = bq >> 2, j0 = (bq & 3) * 64;
        int jj = tid & 63, db = tid >> 6;
#pragma unroll
        for (int k = 0; k < 32; ++k) {
            int dd = db + 4 * k;
            float raw = Q[((size_t)b * D_ + dd) * LQ_ + j0 + jj];
            T[dd][jj] = raw;
            Mb[((size_t)(b * 256 + dd)) * LQ_ + j0 + jj] = f2b(raw);
        }
        __syncthreads();
        {
            float p = 0.f;
#pragma unroll
            for (int k = 0; k < 32; ++k) p += w[D_ + db * 32 + k] * T[db * 32 + k][jj];
            red[db][jj] = p;
        }
        int dq = db * 32;
#pragma unroll
        for (int m = 0; m < 8; ++m) {
            us4 v;
#pragma unroll
            for (int e = 0; e < 4; ++e) v[e] = f2b(T[dq + m * 4 + e][jj]);
            *(us4*)&Qt[((size_t)(b * LQ_ + j0 + jj)) * D_ + dq + m * 4] = v;
        }
        __syncthreads();
        if (tid < 64) {
            int gj = b * LQ_ + j0 + tid;
            rQ[gj] = red[0][tid] + red[1][tid] + red[2][tid] + red[3][tid]
                   + (qmask[gj] ? 0.f : NEGV);
        }
    }
}

// S recomputed per chunk; part[ks][b][j][d] = sum_i exp(S^T+rcm)*Cbf; paz = z partials
// Double-buffered chunk staging: stage(c+1) hidden under chunk c's compute.
__global__ __launch_bounds__(256) void k_sctcmm(
        const unsigned short* __restrict__ Qt, const unsigned short* __restrict__ Cwt,
        const float* __restrict__ rcm, const unsigned short* __restrict__ Cbf,
        float* __restrict__ part, float* __restrict__ paz) {
    __shared__ __align__(16) unsigned short QJ[64 * 128];       // 16 KB
    __shared__ __align__(16) unsigned short CWb[2][64 * 128];   // 2x16 KB
    __shared__ __align__(16) unsigned short Csb[2][128 * 64];   // 2x16 KB
    int bid = blockIdx.x;
    int ks = bid & 3, jt = (bid >> 2) & 3, b = bid >> 4;
    int j0 = jt * 64;
    int tid = threadIdx.x, wv = tid >> 6, lane = tid & 63;
    int jw = wv & 1, dw = wv >> 1;
    int l15 = lane & 15, q = lane >> 4;

#define STAGE_CHUNK(cc, CWdst, Csdst)                                              \
    do {                                                                            \
        int ic_ = ks * 512 + (cc) * 64;                                             \
        _Pragma("unroll")                                                           \
        for (int t = 0; t < 4; ++t) {                                               \
            int G = t * 256 + tid;                                                  \
            int i_ = G >> 4, g_ = G & 15;                                           \
            gld16(Cwt + ((size_t)(b * LC_ + ic_ + i_)) * D_ + ((g_ ^ (i_ & 7)) << 3), \
                  &(CWdst)[G * 8]);                                                 \
        }                                                                           \
        _Pragma("unroll")                                                           \
        for (int t = 0; t < 4; ++t) {                                               \
            int G = t * 256 + tid;                                                  \
            int d_ = G >> 3, g_ = G & 7;                                            \
            gld16(Cbf + ((size_t)(b * D_ + d_)) * LC_ + ic_ + ((g_ ^ (d_ & 7)) << 3), \
                  &(Csdst)[G * 8]);                                                 \
        }                                                                           \
    } while (0)

    // prologue: stage QJ + chunk 0
#pragma unroll
    for (int t = 0; t < 4; ++t) {
        int G = t * 256 + tid;
        int j = G >> 4, g = G & 15;
        gld16(Qt + ((size_t)(b * LQ_ + j0 + j)) * D_ + ((g ^ (j & 7)) << 3), &QJ[G * 8]);
    }
    STAGE_CHUNK(0, CWb[0], Csb[0]);

    f32x4 acc[2][4];
#pragma unroll
    for (int mm = 0; mm < 2; ++mm)
#pragma unroll
        for (int nn = 0; nn < 4; ++nn) acc[mm][nn] = (f32x4){0.f, 0.f, 0.f, 0.f};
    float zac[4] = {0.f, 0.f, 0.f, 0.f};

    __syncthreads();  // QJ + chunk0 visible

    for (int c = 0; c < 8; ++c) {
        int cur = c & 1;
        unsigned short* CW = CWb[cur];
        unsigned short* Cs = Csb[cur];
        int ic = ks * 512 + c * 64;
        // issue next-chunk staging into the other buffer (hidden under compute)
        if (c < 7) STAGE_CHUNK(c + 1, CWb[cur ^ 1], Csb[cur ^ 1]);
        // S-MFMA: reads QJ + CW(cur)
        f32x4 sacc[4];
#pragma unroll
        for (int n = 0; n < 4; ++n) sacc[n] = (f32x4){0.f, 0.f, 0.f, 0.f};
#pragma unroll
        for (int ksd = 0; ksd < 4; ++ksd) {
            int jr = wv * 16 + l15;
            bfrag av = *(const bfrag*)&QJ[jr * 128 + (((ksd * 4 + q) ^ (jr & 7)) << 3)];
#pragma unroll
            for (int n = 0; n < 4; ++n) {
                int ir = n * 16 + l15;
                bfrag bv = *(const bfrag*)&CW[ir * 128 + (((ksd * 4 + q) ^ (ir & 7)) << 3)];
                sacc[n] = __builtin_amdgcn_mfma_f32_16x16x32_bf16(av, bv, sacc[n], 0, 0, 0);
            }
        }
        __syncthreads();  // CW(cur) S-reads done; safe to overwrite with e
#pragma unroll
        for (int n = 0; n < 4; ++n) {
            int i = n * 16 + l15;
            float rc = rcm[b * LC_ + ic + i];
#pragma unroll
            for (int r = 0; r < 4; ++r) {
                int j = wv * 16 + q * 4 + r;
                float e = __expf(sacc[n][r] + rc);
                zac[r] += e;
                *(unsigned short*)((char*)CW + j * 128 +
                    (((i >> 3) ^ (j & 7)) << 4) + (i & 7) * 2) = f2b(e);
            }
        }
        __syncthreads();  // e-bounce visible
#pragma unroll
        for (int kk = 0; kk < 2; ++kk) {
            bfrag afr[2];
#pragma unroll
            for (int mm = 0; mm < 2; ++mm) {
                int j = jw * 32 + mm * 16 + l15;
                afr[mm] = *(const bfrag*)((const char*)CW + j * 128 +
                    (((kk * 4 + q) ^ (j & 7)) << 4));
            }
#pragma unroll
            for (int nn = 0; nn < 4; ++nn) {
                int d = dw * 64 + nn * 16 + l15;
                int g = kk * 4 + q;
                bfrag bv = *(const bfrag*)&Cs[d * 64 + ((g ^ (d & 7)) << 3)];
#pragma unroll
                for (int mm = 0; mm < 2; ++mm)
                    acc[mm][nn] = __builtin_amdgcn_mfma_f32_16x16x32_bf16(afr[mm], bv, acc[mm][nn], 0, 0, 0);
            }
        }
        __syncthreads();  // cur reads done; drains stage(c+1) vmcnt
    }
#undef STAGE_CHUNK
#pragma unroll
    for (int r = 0; r < 4; ++r) {
        zac[r] += __shfl_xor(zac[r], 1, 64);
        zac[r] += __shfl_xor(zac[r], 2, 64);
        zac[r] += __shfl_xor(zac[r], 4, 64);
        zac[r] += __shfl_xor(zac[r], 8, 64);
    }
    if (l15 == 0) {
#pragma unroll
        for (int r = 0; r < 4; ++r)
            paz[((size_t)(ks * B_ + b)) * LQ_ + j0 + wv * 16 + q * 4 + r] = zac[r];
    }
#pragma unroll
    for (int mm = 0; mm < 2; ++mm)
#pragma unroll
        for (int nn = 0; nn < 4; ++nn) {
            int d = dw * 64 + nn * 16 + l15;
#pragma unroll
            for (int r = 0; r < 4; ++r) {
                int j = j0 + jw * 32 + mm * 16 + q * 4 + r;
                part[((size_t)(ks * B_ + b) * LQ_ + j) * D_ + d] = acc[mm][nn][r];
            }
        }
}

// Mb[b][128+d][j] = bf16( sum_ks part / sum_ks paz )  via LDS transpose
__global__ __launch_bounds__(256) void k_red(const float* __restrict__ part,
        const float* __restrict__ paz, unsigned short* __restrict__ Mb) {
    __shared__ float Ts[64][68];
    int bid = blockIdx.x;
    int dt = bid & 1, jt = (bid >> 1) & 3, b = bid >> 3;
    int j0 = jt * 64, d0 = dt * 64;
    int tid = threadIdx.x;
    {
        int jj = tid >> 2, dq = (tid & 3) * 16;
        float zs = paz[((size_t)(0 * B_ + b)) * LQ_ + j0 + jj]
                 + paz[((size_t)(1 * B_ + b)) * LQ_ + j0 + jj]
                 + paz[((size_t)(2 * B_ + b)) * LQ_ + j0 + jj]
                 + paz[((size_t)(3 * B_ + b)) * LQ_ + j0 + jj];
        float rz = 1.0f / zs;
        f4 s[4];
#pragma unroll
        for (int q = 0; q < 4; ++q) s[q] = (f4){0.f, 0.f, 0.f, 0.f};
#pragma unroll
        for (int ks = 0; ks < 4; ++ks) {
            size_t base = ((size_t)(ks * B_ + b) * LQ_ + j0 + jj) * D_ + d0 + dq;
#pragma unroll
            for (int q = 0; q < 4; ++q) s[q] += *(const f4*)&part[base + q * 4];
        }
#pragma unroll
        for (int q = 0; q < 4; ++q) {
            f4 v = {s[q][0] * rz, s[q][1] * rz, s[q][2] * rz, s[q][3] * rz};
            *(f4*)&Ts[jj][dq + q * 4] = v;
        }
    }
    __syncthreads();
    {
        int dd = tid >> 2, jq = (tid & 3) * 16;
        us4 o0, o1, o2, o3;
#pragma unroll
        for (int q = 0; q < 4; ++q) o0[q] = f2b(Ts[jq + q][dd]);
#pragma unroll
        for (int q = 0; q < 4; ++q) o1[q] = f2b(Ts[jq + 4 + q][dd]);
#pragma unroll
        for (int q = 0; q < 4; ++q) o2[q] = f2b(Ts[jq + 8 + q][dd]);
#pragma unroll
        for (int q = 0; q < 4; ++q) o3[q] = f2b(Ts[jq + 12 + q][dd]);
        unsigned short* dst = Mb + ((size_t)(b * 256 + 128 + d0 + dd)) * LQ_ + j0 + jq;
        *(us4*)&dst[0] = o0; *(us4*)&dst[4] = o1; *(us4*)&dst[8] = o2; *(us4*)&dst[12] = o3;
    }
}

// Fused: S-MFMA (QA in LDS, Cwt per-ksd regs) -> e -> P@M -> F in LDS -> relu(W.F+b)
// R11 structure + T5 setprio (R13). UNCHANGED from R13.
__global__ __launch_bounds__(256, 2) void k_rowproj(
        const unsigned short* __restrict__ Qt, const unsigned short* __restrict__ Cwt,
        const float* __restrict__ rQm, const unsigned short* __restrict__ Mb,
        const unsigned short* __restrict__ Cbf, const unsigned short* __restrict__ Wb,
        const float* __restrict__ bres, float* __restrict__ outp) {
    __shared__ __align__(16) unsigned short L[32768];  // 64 KB union (exact)
    unsigned short* QA   = L;                    // ph0: Qt[256 j][128 d] swz (64 KB)
    unsigned short* Ps   = L;                    // e [64 i][256 j-gran] swz (32 KB)
    unsigned short* Ms   = L + 16384;            // M chunks [256 c][64 j] (32 KB)
    float*          Zp   = (float*)(L + 16384);  // z partials, bytes [32K:33K)
    unsigned short* F    = L;                    // proj: F-half [64 i][256 fc] (32 KB)
    unsigned short* WsL  = L + 16384;            // proj: W [128 d][64 k] (16 KB)
    unsigned short* CbfL = L + 24576;            // proj: Cbf [128 d][64 i] (16 KB)

    int bid = blockIdx.x;
    int swz = (bid & 7) * 64 + (bid >> 3);  // XCD swizzle (512 = 8*64, bijective)
    int b = swz >> 5, i0 = (swz & 31) * 64;
    int tid = threadIdx.x, wv = tid >> 6, lane = tid & 63;
    int l15 = lane & 15, q = lane >> 4;

    // ---- phase 0: stage QA (one shot) ----
#pragma unroll
    for (int k = 0; k < 16; ++k) {
        int G = k * 256 + tid;
        int j = G >> 4, g = G & 15;
        gld16(Qt + ((size_t)(b * LQ_ + j)) * D_ + ((g ^ (j & 7)) << 3), &QA[G * 8]);
    }
    __syncthreads();
    // ---- S-MFMA: B-fragments (Cwt) loaded per-ksd (one-shot straight-line) ----
    f32x4 sacc[4][4];
#pragma unroll
    for (int m = 0; m < 4; ++m)
#pragma unroll
        for (int n = 0; n < 4; ++n) sacc[m][n] = (f32x4){0.f, 0.f, 0.f, 0.f};
#pragma unroll
    for (int ksd = 0; ksd < 4; ++ksd) {
        bfrag bv[4];
#pragma unroll
        for (int n = 0; n < 4; ++n)
            bv[n] = *(const bfrag*)&Cwt[
                ((size_t)(b * LC_ + i0 + n * 16 + l15)) * D_ + ksd * 32 + q * 8];
        bfrag av[4];
#pragma unroll
        for (int m = 0; m < 4; ++m) {
            int jr = wv * 64 + m * 16 + l15;
            av[m] = *(const bfrag*)&QA[jr * 128 + (((ksd * 4 + q) ^ (jr & 7)) << 3)];
        }
        __builtin_amdgcn_s_setprio(1);
#pragma unroll
        for (int m = 0; m < 4; ++m)
#pragma unroll
            for (int n = 0; n < 4; ++n)
                sacc[m][n] = __builtin_amdgcn_mfma_f32_16x16x32_bf16(av[m], bv[n], sacc[m][n], 0, 0, 0);
        __builtin_amdgcn_s_setprio(0);
    }
    __syncthreads();  // QA reads done; Ps overlays QA[0:32K), Zp overlays [32K:33K)
    // ---- e + z: Ps[i][j-gran swz], Zp partials ----
    float zp[4] = {0.f, 0.f, 0.f, 0.f};
#pragma unroll
    for (int m = 0; m < 4; ++m) {
        f4 rq4 = *(const f4*)&rQm[b * LQ_ + wv * 64 + m * 16 + q * 4];
#pragma unroll
        for (int n = 0; n < 4; ++n) {
            int i = n * 16 + l15;
#pragma unroll
            for (int r = 0; r < 4; ++r) {
                int j = wv * 64 + m * 16 + q * 4 + r;
                float e = __expf(sacc[m][n][r] + rq4[r]);
                zp[n] += e;
                *(unsigned short*)((char*)Ps + i * 512 +
                    (((j >> 3) ^ (i & 7)) << 4) + (j & 7) * 2) = f2b(e);
            }
        }
    }
#pragma unroll
    for (int n = 0; n < 4; ++n) {
        zp[n] += __shfl_xor(zp[n], 16, 64);
        zp[n] += __shfl_xor(zp[n], 32, 64);
    }
    if (q == 0) {
#pragma unroll
        for (int n = 0; n < 4; ++n) Zp[wv * 64 + n * 16 + l15] = zp[n];
    }
    __syncthreads();  // Zp + Ps visible
    float rzv[4][4];
#pragma unroll
    for (int m = 0; m < 4; ++m)
#pragma unroll
        for (int r = 0; r < 4; ++r) {
            int i = m * 16 + q * 4 + r;
            rzv[m][r] = 1.f / (Zp[i] + Zp[64 + i] + Zp[128 + i] + Zp[192 + i]);
        }

    // ---- phase 2: acc = P @ M ----
    f32x4 acc[4][4];
#pragma unroll
    for (int m = 0; m < 4; ++m)
#pragma unroll
        for (int n = 0; n < 4; ++n) acc[m][n] = (f32x4){0.f, 0.f, 0.f, 0.f};
    for (int jc = 0; jc < 4; ++jc) {
        __syncthreads();  // prev chunk's Ms reads done (jc=0: rzv reads before Ms writes)
#pragma unroll
        for (int t = 0; t < 8; ++t) {
            int G = t * 256 + tid;
            int c = G >> 3, g = G & 7;
            gld16(Mb + ((size_t)(b * 256 + c)) * LQ_ + jc * 64 + ((g ^ (c & 7)) << 3),
                  &Ms[G * 8]);
        }
        __syncthreads();
        __builtin_amdgcn_s_setprio(1);
#pragma unroll
        for (int kk = 0; kk < 2; ++kk) {
            bfrag av[4];
#pragma unroll
            for (int m = 0; m < 4; ++m) {
                int row = m * 16 + l15;
                int gp = (jc * 8 + kk * 4 + q) ^ (row & 7);
                av[m] = *(const bfrag*)((const char*)Ps + row * 512 + (gp << 4));
            }
#pragma unroll
            for (int n = 0; n < 4; ++n) {
                int c = wv * 64 + n * 16 + l15;
                int gb = (kk * 4 + q) ^ (c & 7);
                bfrag bv = *(const bfrag*)((const char*)Ms + c * 128 + (gb << 4));
#pragma unroll
                for (int m = 0; m < 4; ++m)
                    acc[m][n] = __builtin_amdgcn_mfma_f32_16x16x32_bf16(av[m], bv, acc[m][n], 0, 0, 0);
            }
        }
        __builtin_amdgcn_s_setprio(0);
    }

    // ---- fused projection ----
    __syncthreads();  // Ps/Ms reads done
#pragma unroll
    for (int t = 0; t < 4; ++t) {
        int G = t * 256 + tid;
        int d = G >> 3, g = G & 7;
        gld16(Cbf + ((size_t)(b * D_ + d)) * LC_ + i0 + ((g ^ (d & 7)) << 3), &CbfL[G * 8]);
    }
    __syncthreads();

    f32x4 pacc[4][2];
#pragma unroll
    for (int m = 0; m < 4; ++m)
#pragma unroll
        for (int n = 0; n < 2; ++n) pacc[m][n] = (f32x4){0.f, 0.f, 0.f, 0.f};
    int wr = wv >> 1, wc = wv & 1;

#pragma unroll
    for (int fh = 0; fh < 2; ++fh) {
        if (fh == 0) {
            if (wv < 2) {
#pragma unroll
                for (int m = 0; m < 4; ++m) {
                    int ibase = m * 16 + q * 4;
#pragma unroll
                    for (int n = 0; n < 4; ++n) {
                        int fc = 128 + wv * 64 + n * 16 + l15;
#pragma unroll
                        for (int r = 0; r < 4; ++r) {
                            int i = ibase + r;
                            *(unsigned short*)((char*)F + i * 512 +
                                (((fc >> 3) ^ (i & 7)) << 4) + (fc & 7) * 2)
                                = f2b(acc[m][n][r] * rzv[m][r]);
                        }
                    }
                }
            } else {
#pragma unroll
                for (int m = 0; m < 4; ++m) {
#pragma unroll
                    for (int n = 0; n < 4; ++n) {
                        int d = (wv - 2) * 64 + n * 16 + l15;
#pragma unroll
                        for (int r = 0; r < 4; ++r) {
                            int i = m * 16 + q * 4 + r;
                            unsigned short cv = *(const unsigned short*)((const char*)CbfL +
                                d * 128 + (((i >> 3) ^ (d & 7)) << 4) + (i & 7) * 2);
                            *(unsigned short*)((char*)F + i * 512 +
                                (((d >> 3) ^ (i & 7)) << 4) + (d & 7) * 2) = cv;
                        }
                    }
                }
            }
        } else {
#pragma unroll
            for (int m = 0; m < 4; ++m) {
                int ibase = m * 16 + q * 4;
#pragma unroll
                for (int n = 0; n < 4; ++n) {
                    int c = wv * 64 + n * 16 + l15;
                    int d = c & 127;
#pragma unroll
                    for (int r = 0; r < 4; ++r) {
                        int i = ibase + r;
                        float ct = b2f((short)*(const unsigned short*)((const char*)CbfL +
                            d * 128 + (((i >> 3) ^ (d & 7)) << 4) + (i & 7) * 2));
                        *(unsigned short*)((char*)F + i * 512 +
                            (((c >> 3) ^ (i & 7)) << 4) + (c & 7) * 2)
                            = f2b(ct * acc[m][n][r] * rzv[m][r]);
                    }
                }
            }
        }
        __syncthreads();  // F-half ready
#pragma unroll
        for (int kc = 0; kc < 4; ++kc) {
#pragma unroll
            for (int t = 0; t < 4; ++t) {
                int G = t * 256 + tid;
                int d = G >> 3, g = G & 7;
                gld16(Wb + (size_t)d * 512 + fh * 256 + kc * 64 + ((g ^ (d & 7)) << 3),
                      &WsL[G * 8]);
            }
            __syncthreads();
            __builtin_amdgcn_s_setprio(1);
#pragma unroll
            for (int kk = 0; kk < 2; ++kk) {
                bfrag av[4];
#pragma unroll
                for (int m = 0; m < 4; ++m) {
                    int d = wr * 64 + m * 16 + l15;
                    av[m] = *(const bfrag*)((const char*)WsL + d * 128 +
                        (((kk * 4 + q) ^ (d & 7)) << 4));
                }
#pragma unroll
                for (int n = 0; n < 2; ++n) {
                    int i = wc * 32 + n * 16 + l15;
                    int gf = kc * 8 + kk * 4 + q;
                    bfrag bv = *(const bfrag*)((const char*)F + i * 512 +
                        ((gf ^ (i & 7)) << 4));
#pragma unroll
                    for (int m = 0; m < 4; ++m)
                        pacc[m][n] = __builtin_amdgcn_mfma_f32_16x16x32_bf16(av[m], bv, pacc[m][n], 0, 0, 0);
                }
            }
            __builtin_amdgcn_s_setprio(0);
            __syncthreads();
        }
    }
#pragma unroll
    for (int m = 0; m < 4; ++m) {
        int dbase = wr * 64 + m * 16 + q * 4;
        f4 bias = *(const f4*)&bres[dbase];
#pragma unroll
        for (int n = 0; n < 2; ++n) {
            int i = i0 + wc * 32 + n * 16 + l15;
#pragma unroll
            for (int r = 0; r < 4; ++r) {
                float v = pacc[m][n][r] + bias[r];
                outp[((size_t)(b * D_ + dbase + r)) * LC_ + i] = fmaxf(v, 0.f);
            }
        }
    }
}

extern "C" void kernel_launch(void* const* d_in, const int* in_sizes, int n_in,
                              void* d_out, int out_size, void* d_ws, size_t ws_size,
                              hipStream_t stream) {
    const float* C = (const float*)d_in[0];
    const float* Q = (const float*)d_in[1];
    const int* cmask = (const int*)d_in[2];
    const int* qmask = (const int*)d_in[3];
    const float* w = (const float*)d_in[4];
    const float* W_res = (const float*)d_in[5];
    const float* b_res = (const float*)d_in[6];
    float* out = (float*)d_out;
    float* ws = (float*)d_ws;

    float* rC    = ws;                                   // 32768 f (mask folded)
    float* rQ    = rC + 32768;                           // 4096 f
    float* paz   = rQ + 4096;                            // 16384 f
    float* part  = paz + 16384;                          // 2,097,152 f
    float* wbf_f = part + (size_t)2097152;               // Wb (32768 f)
    float* mb_f  = wbf_f + 32768;                        // Mb (524288 f)
    float* cbf_f = mb_f + 524288;                        // Cbf (2,097,152 f)
    float* cwt_f = cbf_f + (size_t)2097152;              // Cwt (2,097,152 f)
    float* qt_f  = cwt_f + (size_t)2097152;              // Qt (262,144 us)

    unsigned short* Wb  = (unsigned short*)wbf_f;
    unsigned short* Mb  = (unsigned short*)mb_f;
    unsigned short* Cbf = (unsigned short*)cbf_f;
    unsigned short* Cwt = (unsigned short*)cwt_f;
    unsigned short* Qt  = (unsigned short*)qt_f;

    k_prep<<<576, 256, 0, stream>>>(C, Q, w, cmask, qmask, W_res,
                                    Cbf, Cwt, Qt, Mb, Wb, rC, rQ);
    k_sctcmm<<<B_ * 16, 256, 0, stream>>>(Qt, Cwt, rC, Cbf, part, paz);
    k_red<<<B_ * 8, 256, 0, stream>>>(part, paz, Mb);
    k_rowproj<<<B_ * 32, 256, 0, stream>>>(Qt, Cwt, rQ, Mb, Cbf, Wb, b_res, out);
}

// Round 16
// 62.468 us; speedup vs baseline: 1.0738x; 1.0738x over previous
//
#include <hip/hip_runtime.h>

// QANet block. B=16 D=128 LC=2048 LQ=256.
// R1..R6: MFMA-ize everything, fuse.             711 -> 84.5 us
// R7: S recomputed in consumers, 4 dispatches.   79.5 us
// R8/R12: per-fragment global loads in loops.    REGRESSED (latency exposed)
// R9/R10: LDS diets.                             no effect — LDS not the cap
// R11: unified VGPR+AGPR cap -> launch_bounds(256,2). 67 us
// R13: + T5 setprio on rowproj MFMA clusters.    66.1 us BEST
// R14: sctcmm dbuf staging.                      NEUTRAL — staging not the issue;
//      sctcmm's real defect: grid 256 = 1 blk/CU = 1 wave/SIMD, drains exposed.
// R15: sctcmm K-split 4->8 (grid 512 = 2 blk/CU, single-buffered 48KB LDS) +
//      setprio on its MFMA clusters; part/paz -> 8 slices; k_red sums 8.
//      rowproj/prep byte-identical to R13.

#define B_ 16
#define D_ 128
#define LC_ 2048
#define LQ_ 256
#define NEGV -1e30f

typedef float f4 __attribute__((ext_vector_type(4)));
typedef float f32x4 __attribute__((ext_vector_type(4)));
typedef short bfrag __attribute__((ext_vector_type(8)));
typedef unsigned short us4 __attribute__((ext_vector_type(4)));

__device__ __forceinline__ unsigned short f2b(float x) {
    unsigned u = __float_as_uint(x);
    u += 0x7fff + ((u >> 16) & 1);
    return (unsigned short)(u >> 16);
}

__device__ __forceinline__ float b2f(short s) {
    return __uint_as_float(((unsigned)(unsigned short)s) << 16);
}

__device__ __forceinline__ void gld16(const void* g, void* l) {
    __builtin_amdgcn_global_load_lds(
        (const __attribute__((address_space(1))) unsigned*)g,
        (__attribute__((address_space(3))) unsigned*)l, 16, 0, 0);
}

// merged prep: blocks [0,512): C-side; [512,576): Q-side
__global__ __launch_bounds__(256) void k_prep(const float* __restrict__ C,
        const float* __restrict__ Q, const float* __restrict__ w,
        const int* __restrict__ cmask, const int* __restrict__ qmask,
        const float* __restrict__ W_res,
        unsigned short* __restrict__ Cbf, unsigned short* __restrict__ Cwt,
        unsigned short* __restrict__ Qt, unsigned short* __restrict__ Mb,
        unsigned short* __restrict__ Wb, float* __restrict__ rC,
        float* __restrict__ rQ) {
    __shared__ float T[128][64];
    __shared__ float red[4][64];
    int tid = threadIdx.x;
    if (blockIdx.x < 512) {
        int b = blockIdx.x >> 5, i0 = (blockIdx.x & 31) * 64;
        int ii = tid & 63, db = tid >> 6;
        if (tid < 128) {
            int wo = blockIdx.x * 128 + tid;
            Wb[wo] = f2b(W_res[wo]);
        }
#pragma unroll
        for (int k = 0; k < 32; ++k) {
            int dd = db + 4 * k;
            float raw = C[((size_t)b * D_ + dd) * LC_ + i0 + ii];
            T[dd][ii] = raw;
            Cbf[((size_t)b * D_ + dd) * LC_ + i0 + ii] = f2b(raw);
        }
        __syncthreads();
        {
            float p = 0.f;
#pragma unroll
            for (int k = 0; k < 32; ++k) p += w[db * 32 + k] * T[db * 32 + k][ii];
            red[db][ii] = p;
        }
        int dq = db * 32;
#pragma unroll
        for (int m = 0; m < 8; ++m) {
            us4 v;
#pragma unroll
            for (int e = 0; e < 4; ++e) {
                int d = dq + m * 4 + e;
                v[e] = f2b(w[2 * D_ + d] * T[d][ii]);
            }
            *(us4*)&Cwt[((size_t)(b * LC_ + i0 + ii)) * D_ + dq + m * 4] = v;
        }
        __syncthreads();
        if (tid < 64) {
            int gi = b * LC_ + i0 + tid;
            rC[gi] = red[0][tid] + red[1][tid] + red[2][tid] + red[3][tid]
                   + (cmask[gi] ? 0.f : NEGV);
        }
    } else {
        int bq = blockIdx.x - 512;
        int b = bq >> 2, j0 = (bq & 3) * 64;
        int jj = tid & 63, db = tid >> 6;
#pragma unroll
        for (int k = 0; k < 32; ++k) {
            int dd = db + 4 * k;
            float raw = Q[((size_t)b * D_ + dd) * LQ_ + j0 + jj];
            T[dd][jj] = raw;
            Mb[((size_t)(b * 256 + dd)) * LQ_ + j0 + jj] = f2b(raw);
        }
        __syncthreads();
        {
            float p = 0.f;
#pragma unroll
            for (int k = 0; k < 32; ++k) p += w[D_ + db * 32 + k] * T[db * 32 + k][jj];
            red[db][jj] = p;
        }
        int dq = db * 32;
#pragma unroll
        for (int m = 0; m < 8; ++m) {
            us4 v;
#pragma unroll
            for (int e = 0; e < 4; ++e) v[e] = f2b(T[dq + m * 4 + e][jj]);
            *(us4*)&Qt[((size_t)(b * LQ_ + j0 + jj)) * D_ + dq + m * 4] = v;
        }
        __syncthreads();
        if (tid < 64) {
            int gj = b * LQ_ + j0 + tid;
            rQ[gj] = red[0][tid] + red[1][tid] + red[2][tid] + red[3][tid]
                   + (qmask[gj] ? 0.f : NEGV);
        }
    }
}

// S recomputed per chunk; part[ks][b][j][d] = sum_{i in ks*256..+256} exp(S^T+rcm)*Cbf
// K-split 8: grid 512 = 2 blk/CU. Single-buffered (R13 form) + setprio.
__global__ __launch_bounds__(256) void k_sctcmm(
        const unsigned short* __restrict__ Qt, const unsigned short* __restrict__ Cwt,
        const float* __restrict__ rcm, const unsigned short* __restrict__ Cbf,
        float* __restrict__ part, float* __restrict__ paz) {
    __shared__ __align__(16) unsigned short QJ[64 * 128];
    __shared__ __align__(16) unsigned short CW[64 * 128];
    __shared__ __align__(16) unsigned short Cs[128 * 64];
    int bid = blockIdx.x;
    int ks = bid & 7, jt = (bid >> 3) & 3, b = bid >> 5;
    int j0 = jt * 64;
    int tid = threadIdx.x, wv = tid >> 6, lane = tid & 63;
    int jw = wv & 1, dw = wv >> 1;
    int l15 = lane & 15, q = lane >> 4;

#pragma unroll
    for (int t = 0; t < 4; ++t) {
        int G = t * 256 + tid;
        int j = G >> 4, g = G & 15;
        gld16(Qt + ((size_t)(b * LQ_ + j0 + j)) * D_ + ((g ^ (j & 7)) << 3), &QJ[G * 8]);
    }

    f32x4 acc[2][4];
#pragma unroll
    for (int mm = 0; mm < 2; ++mm)
#pragma unroll
        for (int nn = 0; nn < 4; ++nn) acc[mm][nn] = (f32x4){0.f, 0.f, 0.f, 0.f};
    float zac[4] = {0.f, 0.f, 0.f, 0.f};

    for (int c = 0; c < 4; ++c) {
        int ic = ks * 256 + c * 64;
        __syncthreads();
#pragma unroll
        for (int t = 0; t < 4; ++t) {
            int G = t * 256 + tid;
            int i = G >> 4, g = G & 15;
            gld16(Cwt + ((size_t)(b * LC_ + ic + i)) * D_ + ((g ^ (i & 7)) << 3), &CW[G * 8]);
        }
#pragma unroll
        for (int t = 0; t < 4; ++t) {
            int G = t * 256 + tid;
            int d = G >> 3, g = G & 7;
            gld16(Cbf + ((size_t)(b * D_ + d)) * LC_ + ic + ((g ^ (d & 7)) << 3), &Cs[G * 8]);
        }
        __syncthreads();
        f32x4 sacc[4];
#pragma unroll
        for (int n = 0; n < 4; ++n) sacc[n] = (f32x4){0.f, 0.f, 0.f, 0.f};
        __builtin_amdgcn_s_setprio(1);
#pragma unroll
        for (int ksd = 0; ksd < 4; ++ksd) {
            int jr = wv * 16 + l15;
            bfrag av = *(const bfrag*)&QJ[jr * 128 + (((ksd * 4 + q) ^ (jr & 7)) << 3)];
#pragma unroll
            for (int n = 0; n < 4; ++n) {
                int ir = n * 16 + l15;
                bfrag bv = *(const bfrag*)&CW[ir * 128 + (((ksd * 4 + q) ^ (ir & 7)) << 3)];
                sacc[n] = __builtin_amdgcn_mfma_f32_16x16x32_bf16(av, bv, sacc[n], 0, 0, 0);
            }
        }
        __builtin_amdgcn_s_setprio(0);
        __syncthreads();
#pragma unroll
        for (int n = 0; n < 4; ++n) {
            int i = n * 16 + l15;
            float rc = rcm[b * LC_ + ic + i];
#pragma unroll
            for (int r = 0; r < 4; ++r) {
                int j = wv * 16 + q * 4 + r;
                float e = __expf(sacc[n][r] + rc);
                zac[r] += e;
                *(unsigned short*)((char*)CW + j * 128 +
                    (((i >> 3) ^ (j & 7)) << 4) + (i & 7) * 2) = f2b(e);
            }
        }
        __syncthreads();
        __builtin_amdgcn_s_setprio(1);
#pragma unroll
        for (int kk = 0; kk < 2; ++kk) {
            bfrag afr[2];
#pragma unroll
            for (int mm = 0; mm < 2; ++mm) {
                int j = jw * 32 + mm * 16 + l15;
                afr[mm] = *(const bfrag*)((const char*)CW + j * 128 +
                    (((kk * 4 + q) ^ (j & 7)) << 4));
            }
#pragma unroll
            for (int nn = 0; nn < 4; ++nn) {
                int d = dw * 64 + nn * 16 + l15;
                int g = kk * 4 + q;
                bfrag bv = *(const bfrag*)&Cs[d * 64 + ((g ^ (d & 7)) << 3)];
#pragma unroll
                for (int mm = 0; mm < 2; ++mm)
                    acc[mm][nn] = __builtin_amdgcn_mfma_f32_16x16x32_bf16(afr[mm], bv, acc[mm][nn], 0, 0, 0);
            }
        }
        __builtin_amdgcn_s_setprio(0);
    }
#pragma unroll
    for (int r = 0; r < 4; ++r) {
        zac[r] += __shfl_xor(zac[r], 1, 64);
        zac[r] += __shfl_xor(zac[r], 2, 64);
        zac[r] += __shfl_xor(zac[r], 4, 64);
        zac[r] += __shfl_xor(zac[r], 8, 64);
    }
    if (l15 == 0) {
#pragma unroll
        for (int r = 0; r < 4; ++r)
            paz[((size_t)(ks * B_ + b)) * LQ_ + j0 + wv * 16 + q * 4 + r] = zac[r];
    }
#pragma unroll
    for (int mm = 0; mm < 2; ++mm)
#pragma unroll
        for (int nn = 0; nn < 4; ++nn) {
            int d = dw * 64 + nn * 16 + l15;
#pragma unroll
            for (int r = 0; r < 4; ++r) {
                int j = j0 + jw * 32 + mm * 16 + q * 4 + r;
                part[((size_t)(ks * B_ + b) * LQ_ + j) * D_ + d] = acc[mm][nn][r];
            }
        }
}

// Mb[b][128+d][j] = bf16( sum_{ks<8} part / sum_{ks<8} paz )  via LDS transpose
__global__ __launch_bounds__(256) void k_red(const float* __restrict__ part,
        const float* __restrict__ paz, unsigned short* __restrict__ Mb) {
    __shared__ float Ts[64][68];
    int bid = blockIdx.x;
    int dt = bid & 1, jt = (bid >> 1) & 3, b = bid >> 3;
    int j0 = jt * 64, d0 = dt * 64;
    int tid = threadIdx.x;
    {
        int jj = tid >> 2, dq = (tid & 3) * 16;
        float zs = 0.f;
#pragma unroll
        for (int ks = 0; ks < 8; ++ks)
            zs += paz[((size_t)(ks * B_ + b)) * LQ_ + j0 + jj];
        float rz = 1.0f / zs;
        f4 s[4];
#pragma unroll
        for (int q = 0; q < 4; ++q) s[q] = (f4){0.f, 0.f, 0.f, 0.f};
#pragma unroll
        for (int ks = 0; ks < 8; ++ks) {
            size_t base = ((size_t)(ks * B_ + b) * LQ_ + j0 + jj) * D_ + d0 + dq;
#pragma unroll
            for (int q = 0; q < 4; ++q) s[q] += *(const f4*)&part[base + q * 4];
        }
#pragma unroll
        for (int q = 0; q < 4; ++q) {
            f4 v = {s[q][0] * rz, s[q][1] * rz, s[q][2] * rz, s[q][3] * rz};
            *(f4*)&Ts[jj][dq + q * 4] = v;
        }
    }
    __syncthreads();
    {
        int dd = tid >> 2, jq = (tid & 3) * 16;
        us4 o0, o1, o2, o3;
#pragma unroll
        for (int q = 0; q < 4; ++q) o0[q] = f2b(Ts[jq + q][dd]);
#pragma unroll
        for (int q = 0; q < 4; ++q) o1[q] = f2b(Ts[jq + 4 + q][dd]);
#pragma unroll
        for (int q = 0; q < 4; ++q) o2[q] = f2b(Ts[jq + 8 + q][dd]);
#pragma unroll
        for (int q = 0; q < 4; ++q) o3[q] = f2b(Ts[jq + 12 + q][dd]);
        unsigned short* dst = Mb + ((size_t)(b * 256 + 128 + d0 + dd)) * LQ_ + j0 + jq;
        *(us4*)&dst[0] = o0; *(us4*)&dst[4] = o1; *(us4*)&dst[8] = o2; *(us4*)&dst[12] = o3;
    }
}

// Fused: S-MFMA (QA in LDS, Cwt per-ksd regs) -> e -> P@M -> F in LDS -> relu(W.F+b)
// R11 structure + T5 setprio. BYTE-IDENTICAL to R13.
__global__ __launch_bounds__(256, 2) void k_rowproj(
        const unsigned short* __restrict__ Qt, const unsigned short* __restrict__ Cwt,
        const float* __restrict__ rQm, const unsigned short* __restrict__ Mb,
        const unsigned short* __restrict__ Cbf, const unsigned short* __restrict__ Wb,
        const float* __restrict__ bres, float* __restrict__ outp) {
    __shared__ __align__(16) unsigned short L[32768];  // 64 KB union (exact)
    unsigned short* QA   = L;                    // ph0: Qt[256 j][128 d] swz (64 KB)
    unsigned short* Ps   = L;                    // e [64 i][256 j-gran] swz (32 KB)
    unsigned short* Ms   = L + 16384;            // M chunks [256 c][64 j] (32 KB)
    float*          Zp   = (float*)(L + 16384);  // z partials, bytes [32K:33K)
    unsigned short* F    = L;                    // proj: F-half [64 i][256 fc] (32 KB)
    unsigned short* WsL  = L + 16384;            // proj: W [128 d][64 k] (16 KB)
    unsigned short* CbfL = L + 24576;            // proj: Cbf [128 d][64 i] (16 KB)

    int bid = blockIdx.x;
    int swz = (bid & 7) * 64 + (bid >> 3);  // XCD swizzle (512 = 8*64, bijective)
    int b = swz >> 5, i0 = (swz & 31) * 64;
    int tid = threadIdx.x, wv = tid >> 6, lane = tid & 63;
    int l15 = lane & 15, q = lane >> 4;

    // ---- phase 0: stage QA (one shot) ----
#pragma unroll
    for (int k = 0; k < 16; ++k) {
        int G = k * 256 + tid;
        int j = G >> 4, g = G & 15;
        gld16(Qt + ((size_t)(b * LQ_ + j)) * D_ + ((g ^ (j & 7)) << 3), &QA[G * 8]);
    }
    __syncthreads();
    // ---- S-MFMA: B-fragments (Cwt) loaded per-ksd (one-shot straight-line) ----
    f32x4 sacc[4][4];
#pragma unroll
    for (int m = 0; m < 4; ++m)
#pragma unroll
        for (int n = 0; n < 4; ++n) sacc[m][n] = (f32x4){0.f, 0.f, 0.f, 0.f};
#pragma unroll
    for (int ksd = 0; ksd < 4; ++ksd) {
        bfrag bv[4];
#pragma unroll
        for (int n = 0; n < 4; ++n)
            bv[n] = *(const bfrag*)&Cwt[
                ((size_t)(b * LC_ + i0 + n * 16 + l15)) * D_ + ksd * 32 + q * 8];
        bfrag av[4];
#pragma unroll
        for (int m = 0; m < 4; ++m) {
            int jr = wv * 64 + m * 16 + l15;
            av[m] = *(const bfrag*)&QA[jr * 128 + (((ksd * 4 + q) ^ (jr & 7)) << 3)];
        }
        __builtin_amdgcn_s_setprio(1);
#pragma unroll
        for (int m = 0; m < 4; ++m)
#pragma unroll
            for (int n = 0; n < 4; ++n)
                sacc[m][n] = __builtin_amdgcn_mfma_f32_16x16x32_bf16(av[m], bv[n], sacc[m][n], 0, 0, 0);
        __builtin_amdgcn_s_setprio(0);
    }
    __syncthreads();  // QA reads done; Ps overlays QA[0:32K), Zp overlays [32K:33K)
    // ---- e + z: Ps[i][j-gran swz], Zp partials ----
    float zp[4] = {0.f, 0.f, 0.f, 0.f};
#pragma unroll
    for (int m = 0; m < 4; ++m) {
        f4 rq4 = *(const f4*)&rQm[b * LQ_ + wv * 64 + m * 16 + q * 4];
#pragma unroll
        for (int n = 0; n < 4; ++n) {
            int i = n * 16 + l15;
#pragma unroll
            for (int r = 0; r < 4; ++r) {
                int j = wv * 64 + m * 16 + q * 4 + r;
                float e = __expf(sacc[m][n][r] + rq4[r]);
                zp[n] += e;
                *(unsigned short*)((char*)Ps + i * 512 +
                    (((j >> 3) ^ (i & 7)) << 4) + (j & 7) * 2) = f2b(e);
            }
        }
    }
#pragma unroll
    for (int n = 0; n < 4; ++n) {
        zp[n] += __shfl_xor(zp[n], 16, 64);
        zp[n] += __shfl_xor(zp[n], 32, 64);
    }
    if (q == 0) {
#pragma unroll
        for (int n = 0; n < 4; ++n) Zp[wv * 64 + n * 16 + l15] = zp[n];
    }
    __syncthreads();  // Zp + Ps visible
    float rzv[4][4];
#pragma unroll
    for (int m = 0; m < 4; ++m)
#pragma unroll
        for (int r = 0; r < 4; ++r) {
            int i = m * 16 + q * 4 + r;
            rzv[m][r] = 1.f / (Zp[i] + Zp[64 + i] + Zp[128 + i] + Zp[192 + i]);
        }

    // ---- phase 2: acc = P @ M ----
    f32x4 acc[4][4];
#pragma unroll
    for (int m = 0; m < 4; ++m)
#pragma unroll
        for (int n = 0; n < 4; ++n) acc[m][n] = (f32x4){0.f, 0.f, 0.f, 0.f};
    for (int jc = 0; jc < 4; ++jc) {
        __syncthreads();  // prev chunk's Ms reads done (jc=0: rzv reads before Ms writes)
#pragma unroll
        for (int t = 0; t < 8; ++t) {
            int G = t * 256 + tid;
            int c = G >> 3, g = G & 7;
            gld16(Mb + ((size_t)(b * 256 + c)) * LQ_ + jc * 64 + ((g ^ (c & 7)) << 3),
                  &Ms[G * 8]);
        }
        __syncthreads();
        __builtin_amdgcn_s_setprio(1);
#pragma unroll
        for (int kk = 0; kk < 2; ++kk) {
            bfrag av[4];
#pragma unroll
            for (int m = 0; m < 4; ++m) {
                int row = m * 16 + l15;
                int gp = (jc * 8 + kk * 4 + q) ^ (row & 7);
                av[m] = *(const bfrag*)((const char*)Ps + row * 512 + (gp << 4));
            }
#pragma unroll
            for (int n = 0; n < 4; ++n) {
                int c = wv * 64 + n * 16 + l15;
                int gb = (kk * 4 + q) ^ (c & 7);
                bfrag bv = *(const bfrag*)((const char*)Ms + c * 128 + (gb << 4));
#pragma unroll
                for (int m = 0; m < 4; ++m)
                    acc[m][n] = __builtin_amdgcn_mfma_f32_16x16x32_bf16(av[m], bv, acc[m][n], 0, 0, 0);
            }
        }
        __builtin_amdgcn_s_setprio(0);
    }

    // ---- fused projection ----
    __syncthreads();  // Ps/Ms reads done
#pragma unroll
    for (int t = 0; t < 4; ++t) {
        int G = t * 256 + tid;
        int d = G >> 3, g = G & 7;
        gld16(Cbf + ((size_t)(b * D_ + d)) * LC_ + i0 + ((g ^ (d & 7)) << 3), &CbfL[G * 8]);
    }
    __syncthreads();

    f32x4 pacc[4][2];
#pragma unroll
    for (int m = 0; m < 4; ++m)
#pragma unroll
        for (int n = 0; n < 2; ++n) pacc[m][n] = (f32x4){0.f, 0.f, 0.f, 0.f};
    int wr = wv >> 1, wc = wv & 1;

#pragma unroll
    for (int fh = 0; fh < 2; ++fh) {
        if (fh == 0) {
            if (wv < 2) {
#pragma unroll
                for (int m = 0; m < 4; ++m) {
                    int ibase = m * 16 + q * 4;
#pragma unroll
                    for (int n = 0; n < 4; ++n) {
                        int fc = 128 + wv * 64 + n * 16 + l15;
#pragma unroll
                        for (int r = 0; r < 4; ++r) {
                            int i = ibase + r;
                            *(unsigned short*)((char*)F + i * 512 +
                                (((fc >> 3) ^ (i & 7)) << 4) + (fc & 7) * 2)
                                = f2b(acc[m][n][r] * rzv[m][r]);
                        }
                    }
                }
            } else {
#pragma unroll
                for (int m = 0; m < 4; ++m) {
#pragma unroll
                    for (int n = 0; n < 4; ++n) {
                        int d = (wv - 2) * 64 + n * 16 + l15;
#pragma unroll
                        for (int r = 0; r < 4; ++r) {
                            int i = m * 16 + q * 4 + r;
                            unsigned short cv = *(const unsigned short*)((const char*)CbfL +
                                d * 128 + (((i >> 3) ^ (d & 7)) << 4) + (i & 7) * 2);
                            *(unsigned short*)((char*)F + i * 512 +
                                (((d >> 3) ^ (i & 7)) << 4) + (d & 7) * 2) = cv;
                        }
                    }
                }
            }
        } else {
#pragma unroll
            for (int m = 0; m < 4; ++m) {
                int ibase = m * 16 + q * 4;
#pragma unroll
                for (int n = 0; n < 4; ++n) {
                    int c = wv * 64 + n * 16 + l15;
                    int d = c & 127;
#pragma unroll
                    for (int r = 0; r < 4; ++r) {
                        int i = ibase + r;
                        float ct = b2f((short)*(const unsigned short*)((const char*)CbfL +
                            d * 128 + (((i >> 3) ^ (d & 7)) << 4) + (i & 7) * 2));
                        *(unsigned short*)((char*)F + i * 512 +
                            (((c >> 3) ^ (i & 7)) << 4) + (c & 7) * 2)
                            = f2b(ct * acc[m][n][r] * rzv[m][r]);
                    }
                }
            }
        }
        __syncthreads();  // F-half ready
#pragma unroll
        for (int kc = 0; kc < 4; ++kc) {
#pragma unroll
            for (int t = 0; t < 4; ++t) {
                int G = t * 256 + tid;
                int d = G >> 3, g = G & 7;
                gld16(Wb + (size_t)d * 512 + fh * 256 + kc * 64 + ((g ^ (d & 7)) << 3),
                      &WsL[G * 8]);
            }
            __syncthreads();
            __builtin_amdgcn_s_setprio(1);
#pragma unroll
            for (int kk = 0; kk < 2; ++kk) {
                bfrag av[4];
#pragma unroll
                for (int m = 0; m < 4; ++m) {
                    int d = wr * 64 + m * 16 + l15;
                    av[m] = *(const bfrag*)((const char*)WsL + d * 128 +
                        (((kk * 4 + q) ^ (d & 7)) << 4));
                }
#pragma unroll
                for (int n = 0; n < 2; ++n) {
                    int i = wc * 32 + n * 16 + l15;
                    int gf = kc * 8 + kk * 4 + q;
                    bfrag bv = *(const bfrag*)((const char*)F + i * 512 +
                        ((gf ^ (i & 7)) << 4));
#pragma unroll
                    for (int m = 0; m < 4; ++m)
                        pacc[m][n] = __builtin_amdgcn_mfma_f32_16x16x32_bf16(av[m], bv, pacc[m][n], 0, 0, 0);
                }
            }
            __builtin_amdgcn_s_setprio(0);
            __syncthreads();
        }
    }
#pragma unroll
    for (int m = 0; m < 4; ++m) {
        int dbase = wr * 64 + m * 16 + q * 4;
        f4 bias = *(const f4*)&bres[dbase];
#pragma unroll
        for (int n = 0; n < 2; ++n) {
            int i = i0 + wc * 32 + n * 16 + l15;
#pragma unroll
            for (int r = 0; r < 4; ++r) {
                float v = pacc[m][n][r] + bias[r];
                outp[((size_t)(b * D_ + dbase + r)) * LC_ + i] = fmaxf(v, 0.f);
            }
        }
    }
}

extern "C" void kernel_launch(void* const* d_in, const int* in_sizes, int n_in,
                              void* d_out, int out_size, void* d_ws, size_t ws_size,
                              hipStream_t stream) {
    const float* C = (const float*)d_in[0];
    const float* Q = (const float*)d_in[1];
    const int* cmask = (const int*)d_in[2];
    const int* qmask = (const int*)d_in[3];
    const float* w = (const float*)d_in[4];
    const float* W_res = (const float*)d_in[5];
    const float* b_res = (const float*)d_in[6];
    float* out = (float*)d_out;
    float* ws = (float*)d_ws;

    float* rC    = ws;                                   // 32768 f (mask folded)
    float* rQ    = rC + 32768;                           // 4096 f
    float* paz   = rQ + 4096;                            // 32768 f (8 slices)
    float* part  = paz + 32768;                          // 4,194,304 f (8 slices)
    float* wbf_f = part + (size_t)4194304;               // Wb (32768 f)
    float* mb_f  = wbf_f + 32768;                        // Mb (524288 f)
    float* cbf_f = mb_f + 524288;                        // Cbf (2,097,152 f)
    float* cwt_f = cbf_f + (size_t)2097152;              // Cwt (2,097,152 f)
    float* qt_f  = cwt_f + (size_t)2097152;              // Qt (262,144 us)

    unsigned short* Wb  = (unsigned short*)wbf_f;
    unsigned short* Mb  = (unsigned short*)mb_f;
    unsigned short* Cbf = (unsigned short*)cbf_f;
    unsigned short* Cwt = (unsigned short*)cwt_f;
    unsigned short* Qt  = (unsigned short*)qt_f;

    k_prep<<<576, 256, 0, stream>>>(C, Q, w, cmask, qmask, W_res,
                                    Cbf, Cwt, Qt, Mb, Wb, rC, rQ);
    k_sctcmm<<<B_ * 32, 256, 0, stream>>>(Qt, Cwt, rC, Cbf, part, paz);
    k_red<<<B_ * 8, 256, 0, stream>>>(part, paz, Mb);
    k_rowproj<<<B_ * 32, 256, 0, stream>>>(Qt, Cwt, rQ, Mb, Cbf, Wb, b_res, out);
}